// Round 9
// baseline (1293.493 us; speedup 1.0000x reference)
//
#include <hip/hip_runtime.h>
#include <hip/hip_bf16.h>
#include <cstdint>

// B=16384, L=5, D=1024.  M = 81920 rows.
// scores = x^T (Wq^T Wk) x  ->  Gt[n,k]; u = x@Gt^T; s = rowdot(u,x)/32.
// Pipeline:
//   k_cvt_multi: x->xb ; Wv->Bcat[1024:2048] ; W1->W1b ; W2->W2b  (one kernel)
//   k_gt:        Gt -> Bcat[0:1024]
//   k_gemm256<0>: [u|v] = xb @ Bcat^T -> d_out bf16 [M][2048]
//   k_attn_ln:   scores->softmax->attn, y = LN(attn+x) -> xb in place
//   k_gemm128<1>: h = GELU(y @ W1^T + b1) -> hb      (BM=128,BN=256: no tail)
//   k_gemm128<3>: z = h @ W2^T + b2 + y -> zb bf16
//   k_ln_final_bf: LN(z)*ff_g+ff_b -> d_out fp32
//
// k_gemm256: R6-verified 4-phase BK=64 dbuf-2 schedule (363us, MfmaUtil 43%).
// k_gemm128: same staging/swizzle pattern, BM=128 BN=256, BK=32 ring-3,
//   one barrier per step, counted vmcnt(3) (3 loads/stage in flight).
// XOR swizzle granule^=(row>>1)&3 both sides (0 conflicts, R5/R6-verified).

typedef float f32x4 __attribute__((ext_vector_type(4)));
typedef __bf16 bf16x8 __attribute__((ext_vector_type(8)));

#define DD 1024
#define NROWS 81920L

__device__ __forceinline__ unsigned short f2bf(float f) {
  union { float f; unsigned u; } c; c.f = f;
  unsigned u = c.u;
  return (unsigned short)((u + 0x7FFFu + ((u >> 16) & 1u)) >> 16);  // RNE
}
__device__ __forceinline__ float bf2f(unsigned short b) {
  union { unsigned u; float f; } c; c.u = ((unsigned)b) << 16;
  return c.f;
}
__device__ __forceinline__ void unpack8(uint4 v, float* o) {
  o[0] = bf2f((unsigned short)(v.x & 0xffffu)); o[1] = bf2f((unsigned short)(v.x >> 16));
  o[2] = bf2f((unsigned short)(v.y & 0xffffu)); o[3] = bf2f((unsigned short)(v.y >> 16));
  o[4] = bf2f((unsigned short)(v.z & 0xffffu)); o[5] = bf2f((unsigned short)(v.z >> 16));
  o[6] = bf2f((unsigned short)(v.w & 0xffffu)); o[7] = bf2f((unsigned short)(v.w >> 16));
}
__device__ __forceinline__ void gload_lds16(const void* g, void* l) {
  __builtin_amdgcn_global_load_lds(
      (const __attribute__((address_space(1))) unsigned int*)g,
      (__attribute__((address_space(3))) unsigned int*)l, 16, 0, 0);
}
__device__ __forceinline__ void cvt8(const float* src, unsigned short* dst, long i) {
  f32x4 a = *(const f32x4*)(src + i);
  f32x4 b = *(const f32x4*)(src + i + 4);
  uint4 o;
  o.x = (unsigned)f2bf(a[0]) | ((unsigned)f2bf(a[1]) << 16);
  o.y = (unsigned)f2bf(a[2]) | ((unsigned)f2bf(a[3]) << 16);
  o.z = (unsigned)f2bf(b[0]) | ((unsigned)f2bf(b[1]) << 16);
  o.w = (unsigned)f2bf(b[2]) | ((unsigned)f2bf(b[3]) << 16);
  *(uint4*)(dst + i) = o;
}

// ---------------- fp32 -> bf16, all four tensors in one launch ----------------
__global__ void __launch_bounds__(256) k_cvt_multi(
    const float* __restrict__ x, const float* __restrict__ Wv,
    const float* __restrict__ W1, const float* __restrict__ W2,
    unsigned short* __restrict__ xb, unsigned short* __restrict__ wvb,
    unsigned short* __restrict__ w1b, unsigned short* __restrict__ w2b) {
  const long NE = NROWS * DD;
  const long M2 = (long)DD * DD;
  const long total = NE + 3 * M2;
  long i = ((long)blockIdx.x * blockDim.x + threadIdx.x) * 8;
  const long stride = (long)gridDim.x * blockDim.x * 8;
  for (; i < total; i += stride) {
    if (i < NE) cvt8(x, xb, i);
    else if (i < NE + M2) cvt8(Wv, wvb, i - NE);
    else if (i < NE + 2 * M2) cvt8(W1, w1b, i - NE - M2);
    else cvt8(W2, w2b, i - NE - 2 * M2);
  }
}

// ---------------- Gt[n,k] = sum_e Wk[e,n] * Wq[e,k] ----------------
__global__ void __launch_bounds__(256) k_gt(const float* __restrict__ Wq,
                                            const float* __restrict__ Wk,
                                            unsigned short* __restrict__ Gt) {
  __shared__ float sk[16][16];
  __shared__ float sq[16][64];
  const int tx = threadIdx.x, ty = threadIdx.y;
  const int n0 = blockIdx.y * 16;
  const int k0 = blockIdx.x * 64;
  float acc[4] = {0.f, 0.f, 0.f, 0.f};
  for (int e0 = 0; e0 < 1024; e0 += 16) {
    sk[ty][tx] = Wk[(long)(e0 + ty) * DD + n0 + tx];
    *(f32x4*)&sq[ty][tx * 4] = *(const f32x4*)&Wq[(long)(e0 + ty) * DD + k0 + tx * 4];
    __syncthreads();
#pragma unroll
    for (int ee = 0; ee < 16; ++ee) {
      float kv = sk[ee][ty];
      f32x4 qv = *(const f32x4*)&sq[ee][tx * 4];
      acc[0] += kv * qv[0]; acc[1] += kv * qv[1];
      acc[2] += kv * qv[2]; acc[3] += kv * qv[3];
    }
    __syncthreads();
  }
  uint2 o;
  o.x = (unsigned)f2bf(acc[0]) | ((unsigned)f2bf(acc[1]) << 16);
  o.y = (unsigned)f2bf(acc[2]) | ((unsigned)f2bf(acc[3]) << 16);
  *(uint2*)&Gt[(long)(n0 + ty) * DD + k0 + tx * 4] = o;
}

// ============ 256x256 BT-GEMM, BK=64, dbuf-2, 4-phase (R6-verified) ============
// TRAILV: 0 none, 1 vmcnt(4), 2 vmcnt(0)
#define PHASE(BUFC, KK, MIH, DOSTAGE, STG_ISB, STG_KK, SN, TRAILV)             \
  {                                                                            \
    const char* rb_ = (BUFC) + ((KK) << 14);                                   \
    if ((MIH) == 0) {                                                          \
      _Pragma("unroll") for (int j = 0; j < 4; ++j)                            \
        fb[j] = *(const bf16x8*)(rb_ + boff[j]);                               \
      _Pragma("unroll") for (int i = 0; i < 4; ++i)                            \
        fa[i] = *(const bf16x8*)(rb_ + aoff[i]);                               \
    } else {                                                                   \
      _Pragma("unroll") for (int i = 0; i < 4; ++i)                            \
        fa[i] = *(const bf16x8*)(rb_ + aoff[4 + i]);                           \
    }                                                                          \
    if (DOSTAGE) {                                                             \
      if (STG_ISB) stageB((SN), (STG_KK)); else stageA((SN), (STG_KK));        \
    }                                                                          \
    __builtin_amdgcn_s_barrier();                                              \
    asm volatile("s_waitcnt lgkmcnt(0)" ::: "memory");                         \
    __builtin_amdgcn_sched_barrier(0);                                         \
    __builtin_amdgcn_s_setprio(1);                                             \
    _Pragma("unroll") for (int i = 0; i < 4; ++i)                              \
      _Pragma("unroll") for (int j = 0; j < 4; ++j)                            \
        acc[(MIH) * 4 + i][j] = __builtin_amdgcn_mfma_f32_16x16x32_bf16(       \
            fa[i], fb[j], acc[(MIH) * 4 + i][j], 0, 0, 0);                     \
    __builtin_amdgcn_s_setprio(0);                                             \
    if ((TRAILV) == 1) asm volatile("s_waitcnt vmcnt(4)" ::: "memory");        \
    else if ((TRAILV) == 2) asm volatile("s_waitcnt vmcnt(0)" ::: "memory");   \
    __builtin_amdgcn_s_barrier();                                              \
    asm volatile("" ::: "memory");                                             \
  }

template <int EPI>   // 0: bf16 store
__global__ void __launch_bounds__(512, 2) k_gemm256(
    const unsigned short* __restrict__ A,   // [M,1024] bf16
    const unsigned short* __restrict__ B,   // [N,1024] bf16 (BT layout)
    unsigned short* __restrict__ outb,
    const int ntl2, const int cst) {
  __shared__ __align__(16) char ldsB[131072];
  const int tid = threadIdx.x;
  const int lane = tid & 63;
  const int wid = tid >> 6;
  const int wm = wid >> 2, wn = wid & 3;

  const int nwg = gridDim.x;
  const int cpx = nwg >> 3;
  const int dd = blockIdx.x;
  const int lgc = (dd & 7) * cpx + (dd >> 3);
  const int mt = lgc >> ntl2;
  const int nt = lgc & ((1 << ntl2) - 1);
  const long m0 = (long)mt * 256;
  const int n0 = nt * 256;

  const int q = tid >> 2;
  const int gcol = (((tid & 3) ^ ((q >> 1) & 3)) << 4);
  const char* gA = (const char*)A + (m0 + q) * 2048 + gcol;
  const char* gB = (const char*)B + ((long)n0 + q) * 2048 + gcol;
  const int ldst = tid * 16;

  auto stageA = [&](int s, int kk) {
    char* dst = ldsB + ((s & 1) << 16) + (kk << 14) + ldst;
    const char* src = gA + (long)s * 128 + (kk << 6);
    gload_lds16(src, dst);
    gload_lds16(src + 128 * 2048, dst + 8192);
  };
  auto stageB = [&](int s, int kk) {
    char* dst = ldsB + ((s & 1) << 16) + 32768 + (kk << 14) + ldst;
    const char* src = gB + (long)s * 128 + (kk << 6);
    gload_lds16(src, dst);
    gload_lds16(src + 128 * 2048, dst + 8192);
  };

  const int la = lane & 15, lg = lane >> 4;
  const int cb = ((lg ^ ((la >> 1) & 3)) << 4);
  int aoff[8], boff[4];
#pragma unroll
  for (int mi = 0; mi < 8; ++mi) aoff[mi] = (wm * 128 + mi * 16 + la) * 64 + cb;
#pragma unroll
  for (int nj = 0; nj < 4; ++nj) boff[nj] = 32768 + (wn * 64 + nj * 16 + la) * 64 + cb;

  f32x4 acc[8][4];
#pragma unroll
  for (int mi = 0; mi < 8; ++mi)
#pragma unroll
    for (int nj = 0; nj < 4; ++nj) acc[mi][nj] = f32x4{0.f, 0.f, 0.f, 0.f};

  bf16x8 fa[4], fb[4];

  stageA(0, 0); stageB(0, 0); stageA(0, 1); stageB(0, 1);
  asm volatile("s_waitcnt vmcnt(4)" ::: "memory");
  __builtin_amdgcn_s_barrier();
  asm volatile("" ::: "memory");

  for (int s = 0; s < 15; ++s) {
    const int sn = s + 1;
    char* bufc = ldsB + ((s & 1) << 16);
    PHASE(bufc, 0, 0, true, false, 0, sn, 0);
    PHASE(bufc, 0, 1, true, true,  0, sn, 1);
    PHASE(bufc, 1, 0, true, false, 1, sn, 0);
    PHASE(bufc, 1, 1, true, true,  1, sn, 1);
  }
  {
    char* bufc = ldsB + ((15 & 1) << 16);
    PHASE(bufc, 0, 0, false, false, 0, 16, 0);
    PHASE(bufc, 0, 1, false, false, 0, 16, 2);
    PHASE(bufc, 1, 0, false, false, 1, 16, 0);
    PHASE(bufc, 1, 1, false, false, 1, 16, 0);
  }

  const long rbase = m0 + wm * 128 + (lane >> 4) * 4;
  const int cbase = n0 + wn * 64 + la;
#pragma unroll
  for (int mi = 0; mi < 8; ++mi)
#pragma unroll
    for (int nj = 0; nj < 4; ++nj) {
      const int col = cbase + nj * 16;
#pragma unroll
      for (int t = 0; t < 4; ++t) {
        const long r = rbase + mi * 16 + t;
        outb[r * (long)cst + col] = f2bf(acc[mi][nj][t]);
      }
    }
}

// ============ 128x256 BT-GEMM, BK=32, ring-3, one barrier/step ============
// EPI 1: GELU(acc+bias) bf16.  EPI 2: acc+bias+resid fp32.  EPI 3: ... bf16.
#define STEP128(RBUF, S, DOSTAGE, TAILV)                                       \
  {                                                                            \
    const char* bA_ = lds3 + (RBUF) * 24576;                                   \
    const char* bB_ = bA_ + 8192;                                              \
    bf16x8 fa[4], fb[4];                                                       \
    _Pragma("unroll") for (int i = 0; i < 4; ++i)                              \
      fa[i] = *(const bf16x8*)(bA_ + aoff[i]);                                 \
    _Pragma("unroll") for (int j = 0; j < 4; ++j)                              \
      fb[j] = *(const bf16x8*)(bB_ + boff[j]);                                 \
    if (DOSTAGE) stage((S) + 2, lds3 + (((S) + 2) % 3) * 24576);               \
    __builtin_amdgcn_s_setprio(1);                                             \
    _Pragma("unroll") for (int i = 0; i < 4; ++i)                              \
      _Pragma("unroll") for (int j = 0; j < 4; ++j)                            \
        acc[i][j] = __builtin_amdgcn_mfma_f32_16x16x32_bf16(                   \
            fa[i], fb[j], acc[i][j], 0, 0, 0);                                 \
    __builtin_amdgcn_s_setprio(0);                                             \
    if ((TAILV) == 1) asm volatile("s_waitcnt vmcnt(3)" ::: "memory");         \
    else if ((TAILV) == 2) asm volatile("s_waitcnt vmcnt(0)" ::: "memory");    \
    if ((TAILV) != 3) {                                                        \
      __builtin_amdgcn_s_barrier();                                            \
      asm volatile("" ::: "memory");                                           \
    }                                                                          \
  }

template <int EPI>
__global__ void __launch_bounds__(512, 2) k_gemm128(
    const unsigned short* __restrict__ A,   // [M,1024] bf16
    const unsigned short* __restrict__ B,   // [1024,1024] bf16 (BT)
    unsigned short* __restrict__ outb,
    float* __restrict__ outf,
    const float* __restrict__ bias,
    const unsigned short* __restrict__ resid) {
  // ring-3: slot p at p*24576; A [128 rows][64B] at 0 (8KB), B [256][64B] at +8192
  __shared__ __align__(16) char lds3[73728];
  const int tid = threadIdx.x;
  const int lane = tid & 63;
  const int wid = tid >> 6;
  const int wm = wid >> 2, wn = wid & 3;     // 2 x 4 waves, wave tile 64x64

  const int nwg = gridDim.x;                 // 2560
  const int cpx = nwg >> 3;
  const int dd = blockIdx.x;
  const int lgc = (dd & 7) * cpx + (dd >> 3);
  const int mt = lgc >> 2;                   // 640 m-tiles
  const int nt = lgc & 3;                    // 4 n-tiles
  const long m0 = (long)mt * 128;
  const int n0 = nt * 256;

  const int q = tid >> 2;                    // 0..127
  const int gcol = (((tid & 3) ^ ((q >> 1) & 3)) << 4);
  const char* gA = (const char*)A + (m0 + q) * 2048 + gcol;
  const char* gB = (const char*)B + ((long)n0 + q) * 2048 + gcol;
  const int ldst = tid * 16;

  auto stage = [&](int s, char* base) {
    const char* sa = gA + (long)s * 64;
    const char* sb = gB + (long)s * 64;
    gload_lds16(sa, base + ldst);                          // A rows 0..127
    gload_lds16(sb, base + 8192 + ldst);                   // B rows 0..127
    gload_lds16(sb + 128 * 2048, base + 16384 + ldst);     // B rows 128..255
  };

  const int la = lane & 15, lg = lane >> 4;
  const int cb = ((lg ^ ((la >> 1) & 3)) << 4);
  int aoff[4], boff[4];
#pragma unroll
  for (int mi = 0; mi < 4; ++mi) aoff[mi] = (wm * 64 + mi * 16 + la) * 64 + cb;
#pragma unroll
  for (int nj = 0; nj < 4; ++nj) boff[nj] = (wn * 64 + nj * 16 + la) * 64 + cb;

  f32x4 acc[4][4];
#pragma unroll
  for (int mi = 0; mi < 4; ++mi)
#pragma unroll
    for (int nj = 0; nj < 4; ++nj) acc[mi][nj] = f32x4{0.f, 0.f, 0.f, 0.f};

  stage(0, lds3);
  stage(1, lds3 + 24576);
  asm volatile("s_waitcnt vmcnt(3)" ::: "memory");
  __builtin_amdgcn_s_barrier();
  asm volatile("" ::: "memory");

  for (int st = 0; st < 30; st += 3) {
    STEP128(0, st + 0, true, 1);
    STEP128(1, st + 1, true, 1);
    STEP128(2, st + 2, true, 1);
  }
  STEP128(0, 30, false, 2);
  STEP128(1, 31, false, 3);

  const long rbase = m0 + wm * 64 + (lane >> 4) * 4;
  const int cbase = n0 + wn * 64 + la;
#pragma unroll
  for (int mi = 0; mi < 4; ++mi) {
#pragma unroll
    for (int nj = 0; nj < 4; ++nj) {
      const int col = cbase + nj * 16;
      const float bv = bias[col];
#pragma unroll
      for (int t = 0; t < 4; ++t) {
        const long r = rbase + mi * 16 + t;
        float v = acc[mi][nj][t] + bv;
        if constexpr (EPI == 1) {
          v = 0.5f * v * (1.0f + erff(v * 0.70710678118654752f));
          outb[r * (long)DD + col] = f2bf(v);
        } else if constexpr (EPI == 2) {
          v += bf2f(resid[r * (long)DD + col]);
          outf[r * (long)DD + col] = v;
        } else {
          v += bf2f(resid[r * (long)DD + col]);
          outb[r * (long)DD + col] = f2bf(v);
        }
      }
    }
  }
}

// ---------------- attn + LN (uv interleaved [M][2048]) ----------------
__global__ void __launch_bounds__(256) k_attn_ln(
    const unsigned short* __restrict__ xb, const unsigned short* __restrict__ uv,
    unsigned short* __restrict__ yb, const int* __restrict__ mask,
    const float* __restrict__ att_g, const float* __restrict__ att_b) {
  const int b = blockIdx.x * 4 + (threadIdx.x >> 6);
  const int lane = threadIdx.x & 63;
  const long xbase = (long)b * 5120 + lane * 16;
  const long ubase = (long)b * 10240 + lane * 16;

  float xr[5][16];
  float sc[5];
#pragma unroll
  for (int l = 0; l < 5; ++l) {
    const unsigned short* xp = xb + xbase + l * 1024;
    const unsigned short* up = uv + ubase + l * 2048;
    unpack8(*(const uint4*)xp, xr[l]); unpack8(*(const uint4*)(xp + 8), xr[l] + 8);
    float uu[16];
    unpack8(*(const uint4*)up, uu); unpack8(*(const uint4*)(up + 8), uu + 8);
    float d = 0.f;
#pragma unroll
    for (int c = 0; c < 16; ++c) d += xr[l][c] * uu[c];
#pragma unroll
    for (int off = 32; off; off >>= 1) d += __shfl_xor(d, off);
    sc[l] = d * 0.03125f;
  }
  bool keep[5];
  float m = -1e30f;
#pragma unroll
  for (int l = 0; l < 5; ++l) {
    keep[l] = (mask[l] != 0);
    if (keep[l]) m = fmaxf(m, sc[l]);
  }
  float p[5], s = 0.f;
#pragma unroll
  for (int l = 0; l < 5; ++l) {
    p[l] = keep[l] ? __expf(sc[l] - m) : 0.f;
    s += p[l];
  }
  const float inv = 1.f / s;

  float gg[16], bb[16];
  {
    const float* gp = att_g + lane * 16;
    const float* bp = att_b + lane * 16;
#pragma unroll
    for (int q = 0; q < 4; ++q) {
      f32x4 gv = *(const f32x4*)(gp + q * 4);
      f32x4 bv = *(const f32x4*)(bp + q * 4);
#pragma unroll
      for (int c = 0; c < 4; ++c) { gg[q * 4 + c] = gv[c]; bb[q * 4 + c] = bv[c]; }
    }
  }

#pragma unroll
  for (int l = 0; l < 5; ++l) {
    const unsigned short* vp = uv + ubase + l * 2048 + 1024;
    float vv[16];
    unpack8(*(const uint4*)vp, vv); unpack8(*(const uint4*)(vp + 8), vv + 8);
    const float pl = p[l] * inv;
    float t[16], sm = 0.f, sq = 0.f;
#pragma unroll
    for (int c = 0; c < 16; ++c) {
      t[c] = pl * vv[c] + xr[l][c];
      sm += t[c];
      sq += t[c] * t[c];
    }
#pragma unroll
    for (int off = 32; off; off >>= 1) {
      sm += __shfl_xor(sm, off);
      sq += __shfl_xor(sq, off);
    }
    const float mu = sm * (1.f / 1024.f);
    const float var = sq * (1.f / 1024.f) - mu * mu;
    const float rs = rsqrtf(var + 1e-5f);
    unsigned short r[16];
#pragma unroll
    for (int c = 0; c < 16; ++c) r[c] = f2bf((t[c] - mu) * rs * gg[c] + bb[c]);
    uint4 o0, o1;
    o0.x = (unsigned)r[0] | ((unsigned)r[1] << 16);  o0.y = (unsigned)r[2] | ((unsigned)r[3] << 16);
    o0.z = (unsigned)r[4] | ((unsigned)r[5] << 16);  o0.w = (unsigned)r[6] | ((unsigned)r[7] << 16);
    o1.x = (unsigned)r[8] | ((unsigned)r[9] << 16);  o1.y = (unsigned)r[10] | ((unsigned)r[11] << 16);
    o1.z = (unsigned)r[12] | ((unsigned)r[13] << 16); o1.w = (unsigned)r[14] | ((unsigned)r[15] << 16);
    unsigned short* yp = yb + xbase + l * 1024;
    *(uint4*)yp = o0;
    *(uint4*)(yp + 8) = o1;
  }
}

// ---------------- final LN, bf16 z -> fp32 out ----------------
__global__ void __launch_bounds__(256) k_ln_final_bf(const unsigned short* __restrict__ zb,
                                                     float* __restrict__ out,
                                                     const float* __restrict__ g,
                                                     const float* __restrict__ bb) {
  const int lane = threadIdx.x & 63;
  const long row = (long)blockIdx.x * 4 + (threadIdx.x >> 6);
  const unsigned short* p = zb + row * DD + lane * 16;
  float t[16];
  unpack8(*(const uint4*)p, t);
  unpack8(*(const uint4*)(p + 8), t + 8);
  float sm = 0.f, sq = 0.f;
#pragma unroll
  for (int c = 0; c < 16; ++c) { sm += t[c]; sq += t[c] * t[c]; }
#pragma unroll
  for (int off = 32; off; off >>= 1) {
    sm += __shfl_xor(sm, off);
    sq += __shfl_xor(sq, off);
  }
  const float mu = sm * (1.f / 1024.f);
  const float var = sq * (1.f / 1024.f) - mu * mu;
  const float rs = rsqrtf(var + 1e-5f);
  float* op = out + row * DD + lane * 16;
  const float* gp = g + lane * 16;
  const float* bp = bb + lane * 16;
#pragma unroll
  for (int q = 0; q < 4; ++q) {
    f32x4 gv = *(const f32x4*)(gp + q * 4);
    f32x4 bv = *(const f32x4*)(bp + q * 4);
    f32x4 o;
#pragma unroll
    for (int c = 0; c < 4; ++c) o[c] = (t[q * 4 + c] - mu) * rs * gv[c] + bv[c];
    *(f32x4*)(op + q * 4) = o;
  }
}

// ---------------- final LN, fp32 z in-place (fallback, small ws) ----------------
__global__ void __launch_bounds__(256) k_ln_final(float* __restrict__ z,
                                                  const float* __restrict__ g,
                                                  const float* __restrict__ bb) {
  const int lane = threadIdx.x & 63;
  const long row = (long)blockIdx.x * 4 + (threadIdx.x >> 6);
  float* p = z + row * DD + lane * 16;
  f32x4 v[4];
  float sm = 0.f, sq = 0.f;
#pragma unroll
  for (int q = 0; q < 4; ++q) {
    v[q] = *(const f32x4*)(p + q * 4);
#pragma unroll
    for (int c = 0; c < 4; ++c) { sm += v[q][c]; sq += v[q][c] * v[q][c]; }
  }
#pragma unroll
  for (int off = 32; off; off >>= 1) {
    sm += __shfl_xor(sm, off);
    sq += __shfl_xor(sq, off);
  }
  const float mu = sm * (1.f / 1024.f);
  const float var = sq * (1.f / 1024.f) - mu * mu;
  const float rs = rsqrtf(var + 1e-5f);
  const float* gp = g + lane * 16;
  const float* bp = bb + lane * 16;
#pragma unroll
  for (int q = 0; q < 4; ++q) {
    f32x4 gv = *(const f32x4*)(gp + q * 4);
    f32x4 bv = *(const f32x4*)(bp + q * 4);
#pragma unroll
    for (int c = 0; c < 4; ++c) v[q][c] = (v[q][c] - mu) * rs * gv[c] + bv[c];
    *(f32x4*)(p + q * 4) = v[q];
  }
}

extern "C" void kernel_launch(void* const* d_in, const int* in_sizes, int n_in,
                              void* d_out, int out_size, void* d_ws, size_t ws_size,
                              hipStream_t stream) {
  const float* x     = (const float*)d_in[0];
  const int*   mask  = (const int*)d_in[1];
  const float* Wq    = (const float*)d_in[2];
  const float* Wk    = (const float*)d_in[3];
  const float* Wv    = (const float*)d_in[4];
  const float* W1    = (const float*)d_in[5];
  const float* b1    = (const float*)d_in[6];
  const float* W2    = (const float*)d_in[7];
  const float* b2    = (const float*)d_in[8];
  const float* att_g = (const float*)d_in[9];
  const float* att_b = (const float*)d_in[10];
  const float* ff_g  = (const float*)d_in[11];
  const float* ff_b  = (const float*)d_in[12];

  const long NE = NROWS * DD;
  unsigned short* xb   = (unsigned short*)d_ws;      // bf16 x, becomes y in place
  unsigned short* hb   = xb + NE;                    // GELU output
  unsigned short* Bcat = hb + NE;                    // [Gt ; Wv]  (2048 x 1024)
  unsigned short* W1b  = Bcat + 2L * DD * DD;
  unsigned short* W2b  = W1b + (long)DD * DD;
  unsigned short* zb   = W2b + (long)DD * DD;        // bf16 z (optional)

  const size_t need_zb = (size_t)(3L * NE + 4L * DD * DD) * 2;
  const bool use_zb = ws_size >= need_zb;

  unsigned short* uvb = (unsigned short*)d_out;      // [M][2048] bf16, exact fit
  float* outf = (float*)d_out;

  k_cvt_multi<<<2048, 256, 0, stream>>>(x, Wv, W1, W2,
                                        xb, Bcat + (long)DD * DD, W1b, W2b);
  k_gt<<<dim3(16, 64), dim3(16, 16), 0, stream>>>(Wq, Wk, Bcat);

  // [u|v] = xb @ Bcat^T : M=81920, N=2048 -> 320*8 blocks (R6-verified 4-phase)
  k_gemm256<0><<<2560, 512, 0, stream>>>(xb, Bcat, uvb, 3, 2048);
  k_attn_ln<<<4096, 256, 0, stream>>>(xb, uvb, xb, mask, att_g, att_b);
  // h = GELU(y @ W1^T + b1) : BM=128 -> 640*4 = 2560 blocks, exactly 5 rounds
  k_gemm128<1><<<2560, 512, 0, stream>>>(xb, W1b, hb, nullptr, b1, nullptr);
  if (use_zb) {
    k_gemm128<3><<<2560, 512, 0, stream>>>(hb, W2b, zb, nullptr, b2, xb);
    k_ln_final_bf<<<20480, 256, 0, stream>>>(zb, outf, ff_g, ff_b);
  } else {
    k_gemm128<2><<<2560, 512, 0, stream>>>(hb, W2b, nullptr, outf, b2, xb);
    k_ln_final<<<20480, 256, 0, stream>>>(outf, ff_g, ff_b);
  }
}